// Round 1
// baseline (3770.321 us; speedup 1.0000x reference)
//
#include <hip/hip_runtime.h>

#define BN_EPS 1e-5f
// B=4, C=64, H=W=64, N=4096, D=8

__global__ void conv1_kernel(const float* __restrict__ x, const float* __restrict__ w,
                             float* __restrict__ out) {
    int idx = blockIdx.x * 256 + threadIdx.x;   // [b][o][y][x]
    int xx = idx & 63, y = (idx >> 6) & 63, o = (idx >> 12) & 63, b = idx >> 18;
    float acc = 0.f;
    #pragma unroll
    for (int i = 0; i < 3; ++i) {
        #pragma unroll
        for (int dy = 0; dy < 3; ++dy) {
            int gy = y + dy - 1;
            if (gy < 0 || gy > 63) continue;
            #pragma unroll
            for (int dx = 0; dx < 3; ++dx) {
                int gx = xx + dx - 1;
                if (gx < 0 || gx > 63) continue;
                acc += w[o*27 + i*9 + dy*3 + dx] * x[(b*3 + i)*4096 + gy*64 + gx];
            }
        }
    }
    out[idx] = acc;
}

__global__ void stats_kernel(const float* __restrict__ t, float* __restrict__ stats) {
    int c = blockIdx.x;          // 64 blocks, one per channel
    int tid = threadIdx.x;
    float s = 0.f, s2 = 0.f;
    for (int b = 0; b < 4; ++b) {
        const float* p = t + (size_t)(b*64 + c)*4096;
        for (int n = tid; n < 4096; n += 256) { float v = p[n]; s += v; s2 += v*v; }
    }
    #pragma unroll
    for (int off = 32; off > 0; off >>= 1) {
        s  += __shfl_down(s, off);
        s2 += __shfl_down(s2, off);
    }
    __shared__ float ls[4], ls2[4];
    int wv = tid >> 6, ln = tid & 63;
    if (ln == 0) { ls[wv] = s; ls2[wv] = s2; }
    __syncthreads();
    if (tid == 0) {
        float S = ls[0]+ls[1]+ls[2]+ls[3], S2 = ls2[0]+ls2[1]+ls2[2]+ls2[3];
        float mean = S / 16384.f;
        float var = S2 / 16384.f - mean*mean;
        stats[c] = mean;
        stats[64+c] = rsqrtf(fmaxf(var, 0.f) + BN_EPS);
    }
}

__global__ void bnrelu_kernel(float* __restrict__ t, const float* __restrict__ stats,
                              const float* __restrict__ g, const float* __restrict__ bb) {
    int idx = blockIdx.x * 256 + threadIdx.x;
    int c = (idx >> 12) & 63;
    float v = (t[idx] - stats[c]) * stats[64+c] * g[c] + bb[c];
    t[idx] = v > 0.f ? v : 0.f;
}

__global__ __launch_bounds__(256) void conv2_kernel(const float* __restrict__ in,
                                                    const float* __restrict__ w,
                                                    float* __restrict__ out) {
    // grid: x=ogroup(4), y=ytile(16), z=b(4)
    int og = blockIdx.x, yt = blockIdx.y, b = blockIdx.z;
    int tid = threadIdx.x;
    int xloc = tid & 63, yloc = tid >> 6;
    int y0 = yt * 4, obase = og * 16;
    __shared__ float xs[16][6][66];
    __shared__ float wl[16][9][16];   // [ci][k][o]
    float acc[16];
    #pragma unroll
    for (int i = 0; i < 16; ++i) acc[i] = 0.f;
    for (int cig = 0; cig < 4; ++cig) {
        int cibase = cig * 16;
        __syncthreads();
        for (int e = tid; e < 16*6*66; e += 256) {
            int ci = e / 396, rem = e % 396, ry = rem / 66, rx = rem % 66;
            int gy = y0 + ry - 1, gx = rx - 1;
            float v = 0.f;
            if (gy >= 0 && gy < 64 && gx >= 0 && gx < 64)
                v = in[(size_t)(b*64 + cibase + ci)*4096 + gy*64 + gx];
            xs[ci][ry][rx] = v;
        }
        for (int e = tid; e < 16*9*16; e += 256) {
            int oo = e & 15, k = (e >> 4) % 9, ci = e / 144;
            wl[ci][k][oo] = w[(size_t)(obase+oo)*576 + (cibase+ci)*9 + k];
        }
        __syncthreads();
        for (int ci = 0; ci < 16; ++ci) {
            #pragma unroll
            for (int k = 0; k < 9; ++k) {
                int dy = k / 3, dx = k % 3;
                float xv = xs[ci][yloc + dy][xloc + dx];
                const float4* wv = (const float4*)&wl[ci][k][0];
                float4 w0 = wv[0], w1 = wv[1], w2 = wv[2], w3 = wv[3];
                acc[0]  += w0.x*xv; acc[1]  += w0.y*xv; acc[2]  += w0.z*xv; acc[3]  += w0.w*xv;
                acc[4]  += w1.x*xv; acc[5]  += w1.y*xv; acc[6]  += w1.z*xv; acc[7]  += w1.w*xv;
                acc[8]  += w2.x*xv; acc[9]  += w2.y*xv; acc[10] += w2.z*xv; acc[11] += w2.w*xv;
                acc[12] += w3.x*xv; acc[13] += w3.y*xv; acc[14] += w3.z*xv; acc[15] += w3.w*xv;
            }
        }
    }
    int y = y0 + yloc;
    #pragma unroll
    for (int oo = 0; oo < 16; ++oo)
        out[(size_t)(b*64 + obase + oo)*4096 + y*64 + xloc] = acc[oo];
}

__global__ __launch_bounds__(256) void qkv_kernel(const float* __restrict__ h,
    const float* __restrict__ qw, const float* __restrict__ qb,
    const float* __restrict__ kw, const float* __restrict__ kb,
    const float* __restrict__ vw, const float* __restrict__ vb,
    int a,
    float* __restrict__ qo, float* __restrict__ ko, float* __restrict__ vo) {
    int b = blockIdx.y;
    int n0 = blockIdx.x * 64;
    int tid = threadIdx.x;
    int nl = tid & 63, r0 = tid >> 6;
    __shared__ float xsh[64][64];
    __shared__ float wsh[80][64];
    __shared__ float bsh[80];
    for (int e = tid; e < 4096; e += 256) {
        int c = e >> 6, n = e & 63;
        xsh[c][n] = h[(size_t)(b*64 + c)*4096 + n0 + n];
    }
    for (int e = tid; e < 5120; e += 256) {
        int r = e >> 6, c = e & 63;
        float wv;
        if (r < 8)       wv = qw[a*512 + r*64 + c];
        else if (r < 16) wv = kw[a*512 + (r-8)*64 + c];
        else             wv = vw[a*4096 + (r-16)*64 + c];
        wsh[r][c] = wv;
    }
    if (tid < 80) {
        float bv;
        if (tid < 8)       bv = qb[a*8 + tid];
        else if (tid < 16) bv = kb[a*8 + tid - 8];
        else               bv = vb[a*64 + tid - 16];
        bsh[tid] = bv;
    }
    __syncthreads();
    for (int r = r0; r < 80; r += 4) {
        float acc = bsh[r];
        #pragma unroll 8
        for (int c = 0; c < 64; ++c) acc += wsh[r][c] * xsh[c][nl];
        int n = n0 + nl;
        if (r < 8)       qo[(size_t)(b*8 + r)*4096 + n] = acc;
        else if (r < 16) ko[(size_t)(b*8 + r - 8)*4096 + n] = acc;
        else             vo[(size_t)(b*64 + r - 16)*4096 + n] = acc;
    }
}

#define TJ 128

__global__ __launch_bounds__(256) void flash_kernel(
    const float* __restrict__ q, const float* __restrict__ k, const float* __restrict__ v,
    const float* __restrict__ hin, float* __restrict__ hout,
    const float* __restrict__ gammas, int a) {
    int b = blockIdx.y;
    int i0 = blockIdx.x * 64;
    int tid = threadIdx.x;
    int il = tid & 63, cs = tid >> 6;   // query-local, channel-slice
    int i = i0 + il;
    int c0 = cs * 16;
    float gamma = gammas[a];
    __shared__ float kt[TJ][8];
    __shared__ float vt[TJ*68];
    __shared__ float smax[4][64];
    float qr[8];
    #pragma unroll
    for (int d = 0; d < 8; ++d) qr[d] = q[(size_t)(b*8 + d)*4096 + i];

    // ---- pass A: row max (j-range split across the 4 waves) ----
    float m = -1e30f;
    for (int j0 = 0; j0 < 4096; j0 += TJ) {
        __syncthreads();
        for (int e = tid; e < TJ*8; e += 256) {
            int d = e >> 7, jj = e & (TJ-1);
            kt[jj][d] = k[(size_t)(b*8 + d)*4096 + j0 + jj];
        }
        __syncthreads();
        #pragma unroll 4
        for (int jj = cs*(TJ/4); jj < (cs+1)*(TJ/4); ++jj) {
            const float4* kp = (const float4*)&kt[jj][0];
            float4 k0 = kp[0], k1 = kp[1];
            float e = qr[0]*k0.x + qr[1]*k0.y + qr[2]*k0.z + qr[3]*k0.w
                    + qr[4]*k1.x + qr[5]*k1.y + qr[6]*k1.z + qr[7]*k1.w;
            m = fmaxf(m, e);
        }
    }
    __syncthreads();
    smax[cs][il] = m;
    __syncthreads();
    m = fmaxf(fmaxf(smax[0][il], smax[1][il]), fmaxf(smax[2][il], smax[3][il]));

    // ---- pass B: exp + PV accumulate (each wave owns 16 channels, all j) ----
    float l = 0.f;
    float acc[16];
    #pragma unroll
    for (int u = 0; u < 16; ++u) acc[u] = 0.f;
    for (int j0 = 0; j0 < 4096; j0 += TJ) {
        __syncthreads();
        for (int e = tid; e < TJ*8; e += 256) {
            int d = e >> 7, jj = e & (TJ-1);
            kt[jj][d] = k[(size_t)(b*8 + d)*4096 + j0 + jj];
        }
        for (int e = tid; e < TJ*64; e += 256) {
            int c = e >> 7, jj = e & (TJ-1);
            vt[jj*68 + c] = v[(size_t)(b*64 + c)*4096 + j0 + jj];
        }
        __syncthreads();
        #pragma unroll 4
        for (int jj = 0; jj < TJ; ++jj) {
            const float4* kp = (const float4*)&kt[jj][0];
            float4 k0 = kp[0], k1 = kp[1];
            float e = qr[0]*k0.x + qr[1]*k0.y + qr[2]*k0.z + qr[3]*k0.w
                    + qr[4]*k1.x + qr[5]*k1.y + qr[6]*k1.z + qr[7]*k1.w;
            float p = __expf(e - m);
            l += p;
            const float4* vp = (const float4*)&vt[jj*68 + c0];
            float4 v0 = vp[0], v1 = vp[1], v2 = vp[2], v3 = vp[3];
            acc[0]  += p*v0.x; acc[1]  += p*v0.y; acc[2]  += p*v0.z; acc[3]  += p*v0.w;
            acc[4]  += p*v1.x; acc[5]  += p*v1.y; acc[6]  += p*v1.z; acc[7]  += p*v1.w;
            acc[8]  += p*v2.x; acc[9]  += p*v2.y; acc[10] += p*v2.z; acc[11] += p*v2.w;
            acc[12] += p*v3.x; acc[13] += p*v3.y; acc[14] += p*v3.z; acc[15] += p*v3.w;
        }
    }
    float s = gamma / l;
    #pragma unroll
    for (int u = 0; u < 16; ++u) {
        int c = c0 + u;
        size_t gi = (size_t)(b*64 + c)*4096 + i;
        hout[gi] = acc[u] * s + hin[gi];
    }
}

__global__ void proj_kernel(const float* __restrict__ h, const float* __restrict__ ow,
                            const float* __restrict__ ob, float* __restrict__ out) {
    int idx = blockIdx.x * 256 + threadIdx.x; // 16384
    int b = idx >> 12, hw = idx & 4095;
    float acc = ob[0];
    #pragma unroll 8
    for (int c = 0; c < 64; ++c) acc += ow[c] * h[(size_t)(b*64 + c)*4096 + hw];
    out[idx] = acc;
}

extern "C" void kernel_launch(void* const* d_in, const int* in_sizes, int n_in,
                              void* d_out, int out_size, void* d_ws, size_t ws_size,
                              hipStream_t stream) {
    const float* x    = (const float*)d_in[0];
    const float* c1w  = (const float*)d_in[1];
    const float* bn1g = (const float*)d_in[2];
    const float* bn1b = (const float*)d_in[3];
    const float* c2w  = (const float*)d_in[4];
    const float* bn2g = (const float*)d_in[5];
    const float* bn2b = (const float*)d_in[6];
    const float* qw   = (const float*)d_in[7];
    const float* qbb  = (const float*)d_in[8];
    const float* kw   = (const float*)d_in[9];
    const float* kbb  = (const float*)d_in[10];
    const float* vw   = (const float*)d_in[11];
    const float* vbb  = (const float*)d_in[12];
    const float* gam  = (const float*)d_in[13];
    const float* ow   = (const float*)d_in[14];
    const float* ob   = (const float*)d_in[15];
    float* out = (float*)d_out;

    float* t1    = (float*)d_ws;          // [4][64][4096]
    float* t2    = t1 + 1048576;          // [4][64][4096]
    float* qg    = t2 + 1048576;          // [4][8][4096]
    float* kg    = qg + 131072;           // [4][8][4096]
    float* vg    = kg + 131072;           // [4][64][4096]
    float* stats = vg + 1048576;          // [128]

    conv1_kernel<<<4096, 256, 0, stream>>>(x, c1w, t1);
    stats_kernel<<<64, 256, 0, stream>>>(t1, stats);
    bnrelu_kernel<<<4096, 256, 0, stream>>>(t1, stats, bn1g, bn1b);
    conv2_kernel<<<dim3(4,16,4), 256, 0, stream>>>(t1, c2w, t2);
    stats_kernel<<<64, 256, 0, stream>>>(t2, stats);
    bnrelu_kernel<<<4096, 256, 0, stream>>>(t2, stats, bn2g, bn2b);

    float* cur = t2; float* oth = t1;
    for (int a = 0; a < 4; ++a) {
        qkv_kernel<<<dim3(64,4), 256, 0, stream>>>(cur, qw, qbb, kw, kbb, vw, vbb, a, qg, kg, vg);
        flash_kernel<<<dim3(64,4), 256, 0, stream>>>(qg, kg, vg, cur, oth, gam, a);
        float* tmp = cur; cur = oth; oth = tmp;
    }
    proj_kernel<<<64, 256, 0, stream>>>(cur, ow, ob, out);
}

// Round 3
// 754.378 us; speedup vs baseline: 4.9979x; 4.9979x over previous
//
#include <hip/hip_runtime.h>

#define BN_EPS 1e-5f
// B=4, C=64, H=W=64, N=4096, D=8

typedef __attribute__((ext_vector_type(8))) short short8v;
typedef __attribute__((ext_vector_type(4))) float float4v;

__device__ inline unsigned short f2bf(float f) {
    unsigned u = __float_as_uint(f);
    u += 0x7fffu + ((u >> 16) & 1u);   // round-to-nearest-even
    return (unsigned short)(u >> 16);
}

__global__ void conv1_kernel(const float* __restrict__ x, const float* __restrict__ w,
                             float* __restrict__ out) {
    int idx = blockIdx.x * 256 + threadIdx.x;   // [b][o][y][x]
    int xx = idx & 63, y = (idx >> 6) & 63, o = (idx >> 12) & 63, b = idx >> 18;
    float acc = 0.f;
    #pragma unroll
    for (int i = 0; i < 3; ++i) {
        #pragma unroll
        for (int dy = 0; dy < 3; ++dy) {
            int gy = y + dy - 1;
            if (gy < 0 || gy > 63) continue;
            #pragma unroll
            for (int dx = 0; dx < 3; ++dx) {
                int gx = xx + dx - 1;
                if (gx < 0 || gx > 63) continue;
                acc += w[o*27 + i*9 + dy*3 + dx] * x[(b*3 + i)*4096 + gy*64 + gx];
            }
        }
    }
    out[idx] = acc;
}

__global__ void stats_kernel(const float* __restrict__ t, float* __restrict__ stats) {
    int c = blockIdx.x;          // 64 blocks, one per channel
    int tid = threadIdx.x;
    float s = 0.f, s2 = 0.f;
    for (int b = 0; b < 4; ++b) {
        const float* p = t + (size_t)(b*64 + c)*4096;
        for (int n = tid; n < 4096; n += 256) { float v = p[n]; s += v; s2 += v*v; }
    }
    #pragma unroll
    for (int off = 32; off > 0; off >>= 1) {
        s  += __shfl_down(s, off);
        s2 += __shfl_down(s2, off);
    }
    __shared__ float ls[4], ls2[4];
    int wv = tid >> 6, ln = tid & 63;
    if (ln == 0) { ls[wv] = s; ls2[wv] = s2; }
    __syncthreads();
    if (tid == 0) {
        float S = ls[0]+ls[1]+ls[2]+ls[3], S2 = ls2[0]+ls2[1]+ls2[2]+ls2[3];
        float mean = S / 16384.f;
        float var = S2 / 16384.f - mean*mean;
        stats[c] = mean;
        stats[64+c] = rsqrtf(fmaxf(var, 0.f) + BN_EPS);
    }
}

__global__ void bnrelu_kernel(float* __restrict__ t, const float* __restrict__ stats,
                              const float* __restrict__ g, const float* __restrict__ bb) {
    int idx = blockIdx.x * 256 + threadIdx.x;
    int c = (idx >> 12) & 63;
    float v = (t[idx] - stats[c]) * stats[64+c] * g[c] + bb[c];
    t[idx] = v > 0.f ? v : 0.f;
}

__global__ __launch_bounds__(256) void conv2_kernel(const float* __restrict__ in,
                                                    const float* __restrict__ w,
                                                    float* __restrict__ out) {
    // grid: x=ogroup(4), y=ytile(16), z=b(4)
    int og = blockIdx.x, yt = blockIdx.y, b = blockIdx.z;
    int tid = threadIdx.x;
    int xloc = tid & 63, yloc = tid >> 6;
    int y0 = yt * 4, obase = og * 16;
    __shared__ float xs[16][6][66];
    __shared__ float wl[16][9][16];   // [ci][k][o]
    float acc[16];
    #pragma unroll
    for (int i = 0; i < 16; ++i) acc[i] = 0.f;
    for (int cig = 0; cig < 4; ++cig) {
        int cibase = cig * 16;
        __syncthreads();
        for (int e = tid; e < 16*6*66; e += 256) {
            int ci = e / 396, rem = e % 396, ry = rem / 66, rx = rem % 66;
            int gy = y0 + ry - 1, gx = rx - 1;
            float v = 0.f;
            if (gy >= 0 && gy < 64 && gx >= 0 && gx < 64)
                v = in[(size_t)(b*64 + cibase + ci)*4096 + gy*64 + gx];
            xs[ci][ry][rx] = v;
        }
        for (int e = tid; e < 16*9*16; e += 256) {
            int oo = e & 15, k = (e >> 4) % 9, ci = e / 144;
            wl[ci][k][oo] = w[(size_t)(obase+oo)*576 + (cibase+ci)*9 + k];
        }
        __syncthreads();
        for (int ci = 0; ci < 16; ++ci) {
            #pragma unroll
            for (int k = 0; k < 9; ++k) {
                int dy = k / 3, dx = k % 3;
                float xv = xs[ci][yloc + dy][xloc + dx];
                const float4* wv = (const float4*)&wl[ci][k][0];
                float4 w0 = wv[0], w1 = wv[1], w2 = wv[2], w3 = wv[3];
                acc[0]  += w0.x*xv; acc[1]  += w0.y*xv; acc[2]  += w0.z*xv; acc[3]  += w0.w*xv;
                acc[4]  += w1.x*xv; acc[5]  += w1.y*xv; acc[6]  += w1.z*xv; acc[7]  += w1.w*xv;
                acc[8]  += w2.x*xv; acc[9]  += w2.y*xv; acc[10] += w2.z*xv; acc[11] += w2.w*xv;
                acc[12] += w3.x*xv; acc[13] += w3.y*xv; acc[14] += w3.z*xv; acc[15] += w3.w*xv;
            }
        }
    }
    int y = y0 + yloc;
    #pragma unroll
    for (int oo = 0; oo < 16; ++oo)
        out[(size_t)(b*64 + obase + oo)*4096 + y*64 + xloc] = acc[oo];
}

// h (fp32) -> qT/kT [B][4096][8] bf16, vB [B][64][4096] bf16
__global__ __launch_bounds__(256) void qkv_kernel(const float* __restrict__ h,
    const float* __restrict__ qw, const float* __restrict__ qb,
    const float* __restrict__ kw, const float* __restrict__ kb,
    const float* __restrict__ vw, const float* __restrict__ vb,
    int a,
    unsigned short* __restrict__ qT, unsigned short* __restrict__ kT,
    unsigned short* __restrict__ vB) {
    int b = blockIdx.y;
    int n0 = blockIdx.x * 64;
    int tid = threadIdx.x;
    int nl = tid & 63, r0 = tid >> 6;
    __shared__ float xsh[64][64];
    __shared__ float wsh[80][64];
    __shared__ float bsh[80];
    for (int e = tid; e < 4096; e += 256) {
        int c = e >> 6, n = e & 63;
        xsh[c][n] = h[(size_t)(b*64 + c)*4096 + n0 + n];
    }
    for (int e = tid; e < 5120; e += 256) {
        int r = e >> 6, c = e & 63;
        float wv;
        if (r < 8)       wv = qw[a*512 + r*64 + c];
        else if (r < 16) wv = kw[a*512 + (r-8)*64 + c];
        else             wv = vw[a*4096 + (r-16)*64 + c];
        wsh[r][c] = wv;
    }
    if (tid < 80) {
        float bv;
        if (tid < 8)       bv = qb[a*8 + tid];
        else if (tid < 16) bv = kb[a*8 + tid - 8];
        else               bv = vb[a*64 + tid - 16];
        bsh[tid] = bv;
    }
    __syncthreads();
    int n = n0 + nl;
    for (int r = r0; r < 80; r += 4) {
        float acc = bsh[r];
        #pragma unroll 8
        for (int c = 0; c < 64; ++c) acc += wsh[r][c] * xsh[c][nl];
        unsigned short bf = f2bf(acc);
        if (r < 8)       qT[((size_t)b*4096 + n)*8 + r] = bf;
        else if (r < 16) kT[((size_t)b*4096 + n)*8 + (r-8)] = bf;
        else             vB[((size_t)b*64 + (r-16))*4096 + n] = bf;
    }
}

// MFMA flash attention, no LDS. Per wave: 16 queries x 32 channels, all j.
// Swapped-operand QK^T (S^T = K·Q) so P is lane-local in PV B-fragment layout.
// K-row permutation f0(m)=2m-(m&3) makes C/D reg r of tile t equal B-frag elem 4t+r.
__global__ __launch_bounds__(256) void flash_mfma_kernel(
    const unsigned short* __restrict__ qT, const unsigned short* __restrict__ kT,
    const unsigned short* __restrict__ vB,
    const float* __restrict__ hin, float* __restrict__ hout,
    const float* __restrict__ gammas, int a) {
    int b = blockIdx.y;
    int tid = threadIdx.x;
    int w = tid >> 6, ln = tid & 63;
    int iw = w & 1, cw = w >> 1;
    int li = ln & 15, g = ln >> 4;
    int i0 = blockIdx.x * 32 + iw * 16;
    int c0 = cw * 32;
    float gamma = gammas[a];

    const unsigned short* qTb = qT + (size_t)b * 4096 * 8;
    const unsigned short* kTb = kT + (size_t)b * 4096 * 8;
    const unsigned short* vBb = vB + (size_t)b * 64 * 4096;

    const short8v zf = {0,0,0,0,0,0,0,0};
    // Q fragment (loop-invariant B-operand): k-slot 8g+e -> d; only g==0 real (d<8)
    short8v qf = zf;
    if (g == 0) qf = *(const short8v*)(qTb + (size_t)(i0 + li) * 8);

    int jp = 2*li - (li & 3);    // f0(li): permuted K-row for A-operand tile 0

    // ---- pass A: full row max ----
    float m = -1e30f;
    for (int j0 = 0; j0 < 4096; j0 += 32) {
        short8v kf0 = zf, kf1 = zf;
        if (g == 0) {
            kf0 = *(const short8v*)(kTb + (size_t)(j0 + jp) * 8);
            kf1 = *(const short8v*)(kTb + (size_t)(j0 + jp + 4) * 8);
        }
        float4v s0 = {0.f,0.f,0.f,0.f}, s1 = {0.f,0.f,0.f,0.f};
        s0 = __builtin_amdgcn_mfma_f32_16x16x32_bf16(kf0, qf, s0, 0, 0, 0);
        s1 = __builtin_amdgcn_mfma_f32_16x16x32_bf16(kf1, qf, s1, 0, 0, 0);
        m = fmaxf(m, fmaxf(fmaxf(s0[0], s0[1]), fmaxf(s0[2], s0[3])));
        m = fmaxf(m, fmaxf(fmaxf(s1[0], s1[1]), fmaxf(s1[2], s1[3])));
    }
    m = fmaxf(m, __shfl_xor(m, 16));
    m = fmaxf(m, __shfl_xor(m, 32));

    // ---- pass B: P = exp(S - m), PV accumulate ----
    float4v acc0 = {0.f,0.f,0.f,0.f}, acc1 = {0.f,0.f,0.f,0.f};
    float lsum = 0.f;
    const unsigned short* vrow0 = vBb + (size_t)(c0 + li) * 4096 + 8*g;
    const unsigned short* vrow1 = vBb + (size_t)(c0 + 16 + li) * 4096 + 8*g;
    for (int j0 = 0; j0 < 4096; j0 += 32) {
        short8v kf0 = zf, kf1 = zf;
        if (g == 0) {
            kf0 = *(const short8v*)(kTb + (size_t)(j0 + jp) * 8);
            kf1 = *(const short8v*)(kTb + (size_t)(j0 + jp + 4) * 8);
        }
        short8v vf0 = *(const short8v*)(vrow0 + j0);
        short8v vf1 = *(const short8v*)(vrow1 + j0);
        float4v s0 = {0.f,0.f,0.f,0.f}, s1 = {0.f,0.f,0.f,0.f};
        s0 = __builtin_amdgcn_mfma_f32_16x16x32_bf16(kf0, qf, s0, 0, 0, 0);
        s1 = __builtin_amdgcn_mfma_f32_16x16x32_bf16(kf1, qf, s1, 0, 0, 0);
        short8v pf;
        float p;
        p = __expf(s0[0] - m); lsum += p; pf[0] = (short)f2bf(p);
        p = __expf(s0[1] - m); lsum += p; pf[1] = (short)f2bf(p);
        p = __expf(s0[2] - m); lsum += p; pf[2] = (short)f2bf(p);
        p = __expf(s0[3] - m); lsum += p; pf[3] = (short)f2bf(p);
        p = __expf(s1[0] - m); lsum += p; pf[4] = (short)f2bf(p);
        p = __expf(s1[1] - m); lsum += p; pf[5] = (short)f2bf(p);
        p = __expf(s1[2] - m); lsum += p; pf[6] = (short)f2bf(p);
        p = __expf(s1[3] - m); lsum += p; pf[7] = (short)f2bf(p);
        acc0 = __builtin_amdgcn_mfma_f32_16x16x32_bf16(vf0, pf, acc0, 0, 0, 0);
        acc1 = __builtin_amdgcn_mfma_f32_16x16x32_bf16(vf1, pf, acc1, 0, 0, 0);
    }
    lsum += __shfl_xor(lsum, 16);
    lsum += __shfl_xor(lsum, 32);
    float inv = gamma / lsum;

    int i = i0 + li;
    #pragma unroll
    for (int r = 0; r < 4; ++r) {
        int c = c0 + 4*g + r;
        size_t gi = ((size_t)(b*64 + c)) * 4096 + i;
        hout[gi] = acc0[r] * inv + hin[gi];
        gi += 16 * 4096;
        hout[gi] = acc1[r] * inv + hin[gi];
    }
}

__global__ void proj_kernel(const float* __restrict__ h, const float* __restrict__ ow,
                            const float* __restrict__ ob, float* __restrict__ out) {
    int idx = blockIdx.x * 256 + threadIdx.x; // 16384
    int b = idx >> 12, hw = idx & 4095;
    float acc = ob[0];
    #pragma unroll 8
    for (int c = 0; c < 64; ++c) acc += ow[c] * h[(size_t)(b*64 + c)*4096 + hw];
    out[idx] = acc;
}

extern "C" void kernel_launch(void* const* d_in, const int* in_sizes, int n_in,
                              void* d_out, int out_size, void* d_ws, size_t ws_size,
                              hipStream_t stream) {
    const float* x    = (const float*)d_in[0];
    const float* c1w  = (const float*)d_in[1];
    const float* bn1g = (const float*)d_in[2];
    const float* bn1b = (const float*)d_in[3];
    const float* c2w  = (const float*)d_in[4];
    const float* bn2g = (const float*)d_in[5];
    const float* bn2b = (const float*)d_in[6];
    const float* qw   = (const float*)d_in[7];
    const float* qbb  = (const float*)d_in[8];
    const float* kw   = (const float*)d_in[9];
    const float* kbb  = (const float*)d_in[10];
    const float* vw   = (const float*)d_in[11];
    const float* vbb  = (const float*)d_in[12];
    const float* gam  = (const float*)d_in[13];
    const float* ow   = (const float*)d_in[14];
    const float* ob   = (const float*)d_in[15];
    float* out = (float*)d_out;

    float* t1 = (float*)d_ws;                       // [4][64][4096] f32
    float* t2 = t1 + 1048576;                       // [4][64][4096] f32
    unsigned short* qT = (unsigned short*)(t2 + 1048576);  // [4][4096][8] bf16
    unsigned short* kT = qT + 131072;               // [4][4096][8] bf16
    unsigned short* vB = kT + 131072;               // [4][64][4096] bf16
    float* stats = (float*)(vB + 1048576);          // [128]

    conv1_kernel<<<4096, 256, 0, stream>>>(x, c1w, t1);
    stats_kernel<<<64, 256, 0, stream>>>(t1, stats);
    bnrelu_kernel<<<4096, 256, 0, stream>>>(t1, stats, bn1g, bn1b);
    conv2_kernel<<<dim3(4,16,4), 256, 0, stream>>>(t1, c2w, t2);
    stats_kernel<<<64, 256, 0, stream>>>(t2, stats);
    bnrelu_kernel<<<4096, 256, 0, stream>>>(t2, stats, bn2g, bn2b);

    float* cur = t2; float* oth = t1;
    for (int a = 0; a < 4; ++a) {
        qkv_kernel<<<dim3(64,4), 256, 0, stream>>>(cur, qw, qbb, kw, kbb, vw, vbb, a, qT, kT, vB);
        flash_mfma_kernel<<<dim3(128,4), 256, 0, stream>>>(qT, kT, vB, cur, oth, gam, a);
        float* tmp = cur; cur = oth; oth = tmp;
    }
    proj_kernel<<<64, 256, 0, stream>>>(cur, ow, ob, out);
}

// Round 4
// 589.072 us; speedup vs baseline: 6.4004x; 1.2806x over previous
//
#include <hip/hip_runtime.h>

#define BN_EPS 1e-5f
#define LOG2E 1.44269504f
#define DEFER_THR 11.0f
// B=4, C=64, H=W=64, N=4096, D=8

typedef __attribute__((ext_vector_type(8))) short short8v;
typedef __attribute__((ext_vector_type(4))) float float4v;
typedef __attribute__((ext_vector_type(4))) unsigned uint4v;

__device__ inline unsigned short f2bf(float f) {
    unsigned u = __float_as_uint(f);
    u += 0x7fffu + ((u >> 16) & 1u);   // round-to-nearest-even
    return (unsigned short)(u >> 16);
}

__device__ inline float fexp2(float x) { return __builtin_amdgcn_exp2f(x); }

__device__ inline unsigned cvtpk_bf16(float lo, float hi) {
    unsigned r;
    asm("v_cvt_pk_bf16_f32 %0, %1, %2" : "=v"(r) : "v"(lo), "v"(hi));
    return r;
}

__global__ void conv1_kernel(const float* __restrict__ x, const float* __restrict__ w,
                             float* __restrict__ out) {
    int idx = blockIdx.x * 256 + threadIdx.x;   // [b][o][y][x]
    int xx = idx & 63, y = (idx >> 6) & 63, o = (idx >> 12) & 63, b = idx >> 18;
    float acc = 0.f;
    #pragma unroll
    for (int i = 0; i < 3; ++i) {
        #pragma unroll
        for (int dy = 0; dy < 3; ++dy) {
            int gy = y + dy - 1;
            if (gy < 0 || gy > 63) continue;
            #pragma unroll
            for (int dx = 0; dx < 3; ++dx) {
                int gx = xx + dx - 1;
                if (gx < 0 || gx > 63) continue;
                acc += w[o*27 + i*9 + dy*3 + dx] * x[(b*3 + i)*4096 + gy*64 + gx];
            }
        }
    }
    out[idx] = acc;
}

__global__ void stats_kernel(const float* __restrict__ t, float* __restrict__ stats) {
    int c = blockIdx.x;          // 64 blocks, one per channel
    int tid = threadIdx.x;
    float s = 0.f, s2 = 0.f;
    for (int b = 0; b < 4; ++b) {
        const float* p = t + (size_t)(b*64 + c)*4096;
        for (int n = tid; n < 4096; n += 256) { float v = p[n]; s += v; s2 += v*v; }
    }
    #pragma unroll
    for (int off = 32; off > 0; off >>= 1) {
        s  += __shfl_down(s, off);
        s2 += __shfl_down(s2, off);
    }
    __shared__ float ls[4], ls2[4];
    int wv = tid >> 6, ln = tid & 63;
    if (ln == 0) { ls[wv] = s; ls2[wv] = s2; }
    __syncthreads();
    if (tid == 0) {
        float S = ls[0]+ls[1]+ls[2]+ls[3], S2 = ls2[0]+ls2[1]+ls2[2]+ls2[3];
        float mean = S / 16384.f;
        float var = S2 / 16384.f - mean*mean;
        stats[c] = mean;
        stats[64+c] = rsqrtf(fmaxf(var, 0.f) + BN_EPS);
    }
}

__global__ void bnrelu_kernel(float* __restrict__ t, const float* __restrict__ stats,
                              const float* __restrict__ g, const float* __restrict__ bb) {
    int idx = blockIdx.x * 256 + threadIdx.x;
    int c = (idx >> 12) & 63;
    float v = (t[idx] - stats[c]) * stats[64+c] * g[c] + bb[c];
    t[idx] = v > 0.f ? v : 0.f;
}

__global__ __launch_bounds__(256) void conv2_kernel(const float* __restrict__ in,
                                                    const float* __restrict__ w,
                                                    float* __restrict__ out) {
    // grid: x=ogroup(4), y=ytile(16), z=b(4)
    int og = blockIdx.x, yt = blockIdx.y, b = blockIdx.z;
    int tid = threadIdx.x;
    int xloc = tid & 63, yloc = tid >> 6;
    int y0 = yt * 4, obase = og * 16;
    __shared__ float xs[16][6][66];
    __shared__ float wl[16][9][16];   // [ci][k][o]
    float acc[16];
    #pragma unroll
    for (int i = 0; i < 16; ++i) acc[i] = 0.f;
    for (int cig = 0; cig < 4; ++cig) {
        int cibase = cig * 16;
        __syncthreads();
        for (int e = tid; e < 16*6*66; e += 256) {
            int ci = e / 396, rem = e % 396, ry = rem / 66, rx = rem % 66;
            int gy = y0 + ry - 1, gx = rx - 1;
            float v = 0.f;
            if (gy >= 0 && gy < 64 && gx >= 0 && gx < 64)
                v = in[(size_t)(b*64 + cibase + ci)*4096 + gy*64 + gx];
            xs[ci][ry][rx] = v;
        }
        for (int e = tid; e < 16*9*16; e += 256) {
            int oo = e & 15, k = (e >> 4) % 9, ci = e / 144;
            wl[ci][k][oo] = w[(size_t)(obase+oo)*576 + (cibase+ci)*9 + k];
        }
        __syncthreads();
        for (int ci = 0; ci < 16; ++ci) {
            #pragma unroll
            for (int k = 0; k < 9; ++k) {
                int dy = k / 3, dx = k % 3;
                float xv = xs[ci][yloc + dy][xloc + dx];
                const float4* wv = (const float4*)&wl[ci][k][0];
                float4 w0 = wv[0], w1 = wv[1], w2 = wv[2], w3 = wv[3];
                acc[0]  += w0.x*xv; acc[1]  += w0.y*xv; acc[2]  += w0.z*xv; acc[3]  += w0.w*xv;
                acc[4]  += w1.x*xv; acc[5]  += w1.y*xv; acc[6]  += w1.z*xv; acc[7]  += w1.w*xv;
                acc[8]  += w2.x*xv; acc[9]  += w2.y*xv; acc[10] += w2.z*xv; acc[11] += w2.w*xv;
                acc[12] += w3.x*xv; acc[13] += w3.y*xv; acc[14] += w3.z*xv; acc[15] += w3.w*xv;
            }
        }
    }
    int y = y0 + yloc;
    #pragma unroll
    for (int oo = 0; oo < 16; ++oo)
        out[(size_t)(b*64 + obase + oo)*4096 + y*64 + xloc] = acc[oo];
}

// h (fp32) -> qT/kT [B][4096][8] bf16, vB [B][64][4096] bf16. Q pre-scaled by log2e.
__global__ __launch_bounds__(512) void qkv_kernel(const float* __restrict__ h,
    const float* __restrict__ qw, const float* __restrict__ qb,
    const float* __restrict__ kw, const float* __restrict__ kb,
    const float* __restrict__ vw, const float* __restrict__ vb,
    int a,
    unsigned short* __restrict__ qT, unsigned short* __restrict__ kT,
    unsigned short* __restrict__ vB) {
    int b = blockIdx.y;
    int n0 = blockIdx.x * 64;
    int tid = threadIdx.x;
    int nl = tid & 63, r0 = tid >> 6;
    __shared__ float xsh[64][64];
    __shared__ float wsh[80][64];
    __shared__ float bsh[80];
    for (int e = tid; e < 4096; e += 512) {
        int c = e >> 6, n = e & 63;
        xsh[c][n] = h[(size_t)(b*64 + c)*4096 + n0 + n];
    }
    for (int e = tid; e < 5120; e += 512) {
        int r = e >> 6, c = e & 63;
        float wv;
        if (r < 8)       wv = qw[a*512 + r*64 + c];
        else if (r < 16) wv = kw[a*512 + (r-8)*64 + c];
        else             wv = vw[a*4096 + (r-16)*64 + c];
        wsh[r][c] = wv;
    }
    if (tid < 80) {
        float bv;
        if (tid < 8)       bv = qb[a*8 + tid];
        else if (tid < 16) bv = kb[a*8 + tid - 8];
        else               bv = vb[a*64 + tid - 16];
        bsh[tid] = bv;
    }
    __syncthreads();
    int n = n0 + nl;
    for (int r = r0; r < 80; r += 8) {
        float acc = bsh[r];
        #pragma unroll 8
        for (int c = 0; c < 64; ++c) acc += wsh[r][c] * xsh[c][nl];
        if (r < 8) {
            qT[((size_t)b*4096 + n)*8 + r] = f2bf(acc * LOG2E);
        } else if (r < 16) {
            kT[((size_t)b*4096 + n)*8 + (r-8)] = f2bf(acc);
        } else {
            vB[((size_t)b*64 + (r-16))*4096 + n] = f2bf(acc);
        }
    }
}

// Single-pass online-softmax MFMA flash, j-split across blockIdx.y.
// Per wave: 16 queries x 32 channels over 2048 j. Swapped-operand QK^T
// (S^T = K·Q, Q pre-scaled by log2e) so P is lane-local in PV B-frag layout.
// K-row permutation f0(m)=2m-(m&3): C/D reg r of tile t == B-frag elem 4t+r.
// Writes unnormalized acc + per-query (m, l) partials (log2 domain).
__global__ __launch_bounds__(256) void flash_split_kernel(
    const unsigned short* __restrict__ qT, const unsigned short* __restrict__ kT,
    const unsigned short* __restrict__ vB,
    float* __restrict__ accO0, float* __restrict__ accO1,
    float* __restrict__ mP, float* __restrict__ lP) {
    int b = blockIdx.z;
    int js = blockIdx.y;
    int tid = threadIdx.x;
    int w = tid >> 6, ln = tid & 63;
    int iw = w & 1, cw = w >> 1;
    int li = ln & 15, g = ln >> 4;
    int i0 = blockIdx.x * 32 + iw * 16;
    int c0 = cw * 32;

    const unsigned short* qTb = qT + (size_t)b * 4096 * 8;
    const unsigned short* kTb = kT + (size_t)b * 4096 * 8;
    const unsigned short* vBb = vB + (size_t)b * 64 * 4096;

    const short8v zf = {0,0,0,0,0,0,0,0};
    short8v qf = zf;
    if (g == 0) qf = *(const short8v*)(qTb + (size_t)(i0 + li) * 8);

    int jp = 2*li - (li & 3);    // f0(li)

    const unsigned short* vrow0 = vBb + (size_t)(c0 + li) * 4096 + 8*g;
    const unsigned short* vrow1 = vBb + (size_t)(c0 + 16 + li) * 4096 + 8*g;

    float m_run = -1e30f;
    float lsum = 0.f;
    float4v acc0 = {0.f,0.f,0.f,0.f}, acc1 = {0.f,0.f,0.f,0.f};

    int jbase = js * 2048;
    for (int j0 = jbase; j0 < jbase + 2048; j0 += 32) {
        short8v kf0 = zf, kf1 = zf;
        if (g == 0) {
            kf0 = *(const short8v*)(kTb + (size_t)(j0 + jp) * 8);
            kf1 = *(const short8v*)(kTb + (size_t)(j0 + jp + 4) * 8);
        }
        short8v vf0 = *(const short8v*)(vrow0 + j0);
        short8v vf1 = *(const short8v*)(vrow1 + j0);
        float4v s0 = {0.f,0.f,0.f,0.f}, s1 = {0.f,0.f,0.f,0.f};
        s0 = __builtin_amdgcn_mfma_f32_16x16x32_bf16(kf0, qf, s0, 0, 0, 0);
        s1 = __builtin_amdgcn_mfma_f32_16x16x32_bf16(kf1, qf, s1, 0, 0, 0);

        // per-query tile max (sync across the 4 g-groups of query li)
        float pm = fmaxf(fmaxf(fmaxf(s0[0], s0[1]), fmaxf(s0[2], s0[3])),
                         fmaxf(fmaxf(s1[0], s1[1]), fmaxf(s1[2], s1[3])));
        pm = fmaxf(pm, __shfl_xor(pm, 16));
        pm = fmaxf(pm, __shfl_xor(pm, 32));
        if (pm > m_run + DEFER_THR) {       // defer-max: rescale only on big growth
            float f = fexp2(m_run - pm);
            m_run = pm;
            lsum *= f;
            acc0[0] *= f; acc0[1] *= f; acc0[2] *= f; acc0[3] *= f;
            acc1[0] *= f; acc1[1] *= f; acc1[2] *= f; acc1[3] *= f;
        }

        float p0 = fexp2(s0[0] - m_run), p1 = fexp2(s0[1] - m_run);
        float p2 = fexp2(s0[2] - m_run), p3 = fexp2(s0[3] - m_run);
        float p4 = fexp2(s1[0] - m_run), p5 = fexp2(s1[1] - m_run);
        float p6 = fexp2(s1[2] - m_run), p7 = fexp2(s1[3] - m_run);
        lsum += ((p0 + p1) + (p2 + p3)) + ((p4 + p5) + (p6 + p7));
        uint4v pi;
        pi[0] = cvtpk_bf16(p0, p1);
        pi[1] = cvtpk_bf16(p2, p3);
        pi[2] = cvtpk_bf16(p4, p5);
        pi[3] = cvtpk_bf16(p6, p7);
        short8v pf = __builtin_bit_cast(short8v, pi);
        acc0 = __builtin_amdgcn_mfma_f32_16x16x32_bf16(vf0, pf, acc0, 0, 0, 0);
        acc1 = __builtin_amdgcn_mfma_f32_16x16x32_bf16(vf1, pf, acc1, 0, 0, 0);
    }
    lsum += __shfl_xor(lsum, 16);
    lsum += __shfl_xor(lsum, 32);

    float* accO = (js == 0) ? accO0 : accO1;
    int i = i0 + li;
    #pragma unroll
    for (int r = 0; r < 4; ++r) {
        int c = c0 + 4*g + r;
        accO[((size_t)(b*64 + c)) * 4096 + i] = acc0[r];
        accO[((size_t)(b*64 + c + 16)) * 4096 + i] = acc1[r];
    }
    if (cw == 0 && g == 0) {
        mP[(size_t)(b*2 + js)*4096 + i] = m_run;
        lP[(size_t)(b*2 + js)*4096 + i] = lsum;
    }
}

// Combine the two j-splits (log-sum-exp merge), apply gamma/l and residual.
// In-place over acc0io (becomes hout).
__global__ void merge_kernel(float* __restrict__ acc0io, const float* __restrict__ acc1,
                             const float* __restrict__ mP, const float* __restrict__ lP,
                             const float* __restrict__ hin,
                             const float* __restrict__ gammas, int a) {
    int idx = blockIdx.x * 256 + threadIdx.x;   // 1M
    int i = idx & 4095, b = idx >> 18;
    float m0 = mP[(size_t)(b*2 + 0)*4096 + i], m1 = mP[(size_t)(b*2 + 1)*4096 + i];
    float l0 = lP[(size_t)(b*2 + 0)*4096 + i], l1 = lP[(size_t)(b*2 + 1)*4096 + i];
    float M = fmaxf(m0, m1);
    float w0 = fexp2(m0 - M), w1 = fexp2(m1 - M);
    float l = l0*w0 + l1*w1;
    float o = (acc0io[idx]*w0 + acc1[idx]*w1) * (gammas[a] / l) + hin[idx];
    acc0io[idx] = o;
}

__global__ void proj_kernel(const float* __restrict__ h, const float* __restrict__ ow,
                            const float* __restrict__ ob, float* __restrict__ out) {
    int idx = blockIdx.x * 256 + threadIdx.x; // 16384
    int b = idx >> 12, hw = idx & 4095;
    float acc = ob[0];
    #pragma unroll 8
    for (int c = 0; c < 64; ++c) acc += ow[c] * h[(size_t)(b*64 + c)*4096 + hw];
    out[idx] = acc;
}

extern "C" void kernel_launch(void* const* d_in, const int* in_sizes, int n_in,
                              void* d_out, int out_size, void* d_ws, size_t ws_size,
                              hipStream_t stream) {
    const float* x    = (const float*)d_in[0];
    const float* c1w  = (const float*)d_in[1];
    const float* bn1g = (const float*)d_in[2];
    const float* bn1b = (const float*)d_in[3];
    const float* c2w  = (const float*)d_in[4];
    const float* bn2g = (const float*)d_in[5];
    const float* bn2b = (const float*)d_in[6];
    const float* qw   = (const float*)d_in[7];
    const float* qbb  = (const float*)d_in[8];
    const float* kw   = (const float*)d_in[9];
    const float* kbb  = (const float*)d_in[10];
    const float* vw   = (const float*)d_in[11];
    const float* vbb  = (const float*)d_in[12];
    const float* gam  = (const float*)d_in[13];
    const float* ow   = (const float*)d_in[14];
    const float* ob   = (const float*)d_in[15];
    float* out = (float*)d_out;

    float* t1 = (float*)d_ws;                       // [4][64][4096] f32
    float* t2 = t1 + 1048576;                       // [4][64][4096] f32
    unsigned short* qT = (unsigned short*)(t2 + 1048576);  // [4][4096][8] bf16
    unsigned short* kT = qT + 131072;               // [4][4096][8] bf16
    unsigned short* vB = kT + 131072;               // [4][64][4096] bf16
    float* acc1B = (float*)(vB + 1048576);          // [4][64][4096] f32 (split-1 partial)
    float* mP    = acc1B + 1048576;                 // [4][2][4096]
    float* lP    = mP + 32768;                      // [4][2][4096]
    float* stats = lP + 32768;                      // [128]

    conv1_kernel<<<4096, 256, 0, stream>>>(x, c1w, t1);
    stats_kernel<<<64, 256, 0, stream>>>(t1, stats);
    bnrelu_kernel<<<4096, 256, 0, stream>>>(t1, stats, bn1g, bn1b);
    conv2_kernel<<<dim3(4,16,4), 256, 0, stream>>>(t1, c2w, t2);
    stats_kernel<<<64, 256, 0, stream>>>(t2, stats);
    bnrelu_kernel<<<4096, 256, 0, stream>>>(t2, stats, bn2g, bn2b);

    float* cur = t2; float* oth = t1;
    for (int a = 0; a < 4; ++a) {
        qkv_kernel<<<dim3(64,4), 512, 0, stream>>>(cur, qw, qbb, kw, kbb, vw, vbb, a, qT, kT, vB);
        // split-0 partial goes into `oth`; merge finalizes in-place -> oth becomes hout
        flash_split_kernel<<<dim3(128,2,4), 256, 0, stream>>>(qT, kT, vB, oth, acc1B, mP, lP);
        merge_kernel<<<4096, 256, 0, stream>>>(oth, acc1B, mP, lP, cur, gam, a);
        float* tmp = cur; cur = oth; oth = tmp;
    }
    proj_kernel<<<64, 256, 0, stream>>>(cur, ow, ob, out);
}

// Round 5
// 573.517 us; speedup vs baseline: 6.5740x; 1.0271x over previous
//
#include <hip/hip_runtime.h>

#define BN_EPS 1e-5f
#define LOG2E 1.44269504f
#define DEFER_THR 11.0f
// B=4, C=64, H=W=64, N=4096, D=8

typedef __attribute__((ext_vector_type(8))) short short8v;
typedef __attribute__((ext_vector_type(4))) float float4v;
typedef __attribute__((ext_vector_type(4))) unsigned uint4v;

__device__ inline unsigned short f2bf(float f) {
    unsigned u = __float_as_uint(f);
    u += 0x7fffu + ((u >> 16) & 1u);   // round-to-nearest-even
    return (unsigned short)(u >> 16);
}

__device__ inline float fexp2(float x) { return __builtin_amdgcn_exp2f(x); }

__device__ inline unsigned cvtpk_bf16(float lo, float hi) {
    unsigned r;
    asm("v_cvt_pk_bf16_f32 %0, %1, %2" : "=v"(r) : "v"(lo), "v"(hi));
    return r;
}

__global__ void conv1_kernel(const float* __restrict__ x, const float* __restrict__ w,
                             float* __restrict__ out) {
    int idx = blockIdx.x * 256 + threadIdx.x;   // [b][o][y][x]
    int xx = idx & 63, y = (idx >> 6) & 63, o = (idx >> 12) & 63, b = idx >> 18;
    float acc = 0.f;
    #pragma unroll
    for (int i = 0; i < 3; ++i) {
        #pragma unroll
        for (int dy = 0; dy < 3; ++dy) {
            int gy = y + dy - 1;
            if (gy < 0 || gy > 63) continue;
            #pragma unroll
            for (int dx = 0; dx < 3; ++dx) {
                int gx = xx + dx - 1;
                if (gx < 0 || gx > 63) continue;
                acc += w[o*27 + i*9 + dy*3 + dx] * x[(b*3 + i)*4096 + gy*64 + gx];
            }
        }
    }
    out[idx] = acc;
}

// partial sums per (b,c): 256 blocks
__global__ void stats_part_kernel(const float* __restrict__ t, float* __restrict__ ps) {
    int bc = blockIdx.x;
    int tid = threadIdx.x;
    const float* p = t + (size_t)bc * 4096;
    float s = 0.f, s2 = 0.f;
    for (int n = tid; n < 4096; n += 256) { float v = p[n]; s += v; s2 += v*v; }
    #pragma unroll
    for (int off = 32; off > 0; off >>= 1) {
        s  += __shfl_down(s, off);
        s2 += __shfl_down(s2, off);
    }
    __shared__ float ls[8];
    int wv = tid >> 6, ln = tid & 63;
    if (ln == 0) { ls[wv] = s; ls[4+wv] = s2; }
    __syncthreads();
    if (tid == 0) {
        ps[bc]       = ls[0]+ls[1]+ls[2]+ls[3];
        ps[256 + bc] = ls[4]+ls[5]+ls[6]+ls[7];
    }
}

__global__ void stats_final_kernel(const float* __restrict__ ps, float* __restrict__ stats) {
    int c = threadIdx.x;   // 64
    float S = 0.f, S2 = 0.f;
    #pragma unroll
    for (int b = 0; b < 4; ++b) { S += ps[b*64 + c]; S2 += ps[256 + b*64 + c]; }
    float mean = S / 16384.f;
    float var = S2 / 16384.f - mean*mean;
    stats[c] = mean;
    stats[64+c] = rsqrtf(fmaxf(var, 0.f) + BN_EPS);
}

__global__ void bnrelu_kernel(float* __restrict__ t, const float* __restrict__ stats,
                              const float* __restrict__ g, const float* __restrict__ bb) {
    int idx = blockIdx.x * 256 + threadIdx.x;
    int c = (idx >> 12) & 63;
    float v = (t[idx] - stats[c]) * stats[64+c] * g[c] + bb[c];
    t[idx] = v > 0.f ? v : 0.f;
}

__global__ __launch_bounds__(256) void conv2_kernel(const float* __restrict__ in,
                                                    const float* __restrict__ w,
                                                    float* __restrict__ out) {
    // grid: x=ogroup(16 -> 4 o), y=ytile(16 -> 4 rows), z=b(4)  => 1024 blocks
    int og = blockIdx.x, yt = blockIdx.y, b = blockIdx.z;
    int tid = threadIdx.x;
    int xloc = tid & 63, yloc = tid >> 6;
    int y0 = yt * 4, obase = og * 4;
    __shared__ float xs[16][6][66];
    __shared__ float wl[16][9][4];   // [ci][k][o] (float4-aligned)
    float acc[4] = {0.f, 0.f, 0.f, 0.f};
    for (int cig = 0; cig < 4; ++cig) {
        int cibase = cig * 16;
        __syncthreads();
        for (int e = tid; e < 16*6*66; e += 256) {
            int ci = e / 396, rem = e % 396, ry = rem / 66, rx = rem % 66;
            int gy = y0 + ry - 1, gx = rx - 1;
            float v = 0.f;
            if (gy >= 0 && gy < 64 && gx >= 0 && gx < 64)
                v = in[(size_t)(b*64 + cibase + ci)*4096 + gy*64 + gx];
            xs[ci][ry][rx] = v;
        }
        for (int e = tid; e < 16*9*4; e += 256) {
            int oo = e & 3, k = (e >> 2) % 9, ci = e / 36;
            wl[ci][k][oo] = w[(size_t)(obase+oo)*576 + (cibase+ci)*9 + k];
        }
        __syncthreads();
        for (int ci = 0; ci < 16; ++ci) {
            #pragma unroll
            for (int k = 0; k < 9; ++k) {
                int dy = k / 3, dx = k % 3;
                float xv = xs[ci][yloc + dy][xloc + dx];
                const float4 ww = *(const float4*)&wl[ci][k][0];
                acc[0] += ww.x*xv; acc[1] += ww.y*xv; acc[2] += ww.z*xv; acc[3] += ww.w*xv;
            }
        }
    }
    int y = y0 + yloc;
    #pragma unroll
    for (int oo = 0; oo < 4; ++oo)
        out[(size_t)(b*64 + obase + oo)*4096 + y*64 + xloc] = acc[oo];
}

// h (fp32) -> qT/kT [B][4096][8] bf16, vB [B][64][4096] bf16. Q pre-scaled by log2e.
__global__ __launch_bounds__(512) void qkv_kernel(const float* __restrict__ h,
    const float* __restrict__ qw, const float* __restrict__ qb,
    const float* __restrict__ kw, const float* __restrict__ kb,
    const float* __restrict__ vw, const float* __restrict__ vb,
    int a,
    unsigned short* __restrict__ qT, unsigned short* __restrict__ kT,
    unsigned short* __restrict__ vB) {
    int b = blockIdx.y;
    int n0 = blockIdx.x * 64;
    int tid = threadIdx.x;
    int nl = tid & 63, r0 = tid >> 6;
    __shared__ float xsh[64][64];
    __shared__ float wsh[80][64];
    __shared__ float bsh[80];
    for (int e = tid; e < 4096; e += 512) {
        int c = e >> 6, n = e & 63;
        xsh[c][n] = h[(size_t)(b*64 + c)*4096 + n0 + n];
    }
    for (int e = tid; e < 5120; e += 512) {
        int r = e >> 6, c = e & 63;
        float wv;
        if (r < 8)       wv = qw[a*512 + r*64 + c];
        else if (r < 16) wv = kw[a*512 + (r-8)*64 + c];
        else             wv = vw[a*4096 + (r-16)*64 + c];
        wsh[r][c] = wv;
    }
    if (tid < 80) {
        float bv;
        if (tid < 8)       bv = qb[a*8 + tid];
        else if (tid < 16) bv = kb[a*8 + tid - 8];
        else               bv = vb[a*64 + tid - 16];
        bsh[tid] = bv;
    }
    __syncthreads();
    int n = n0 + nl;
    for (int r = r0; r < 80; r += 8) {
        float acc = bsh[r];
        #pragma unroll 8
        for (int c = 0; c < 64; ++c) acc += wsh[r][c] * xsh[c][nl];
        if (r < 8) {
            qT[((size_t)b*4096 + n)*8 + r] = f2bf(acc * LOG2E);
        } else if (r < 16) {
            kT[((size_t)b*4096 + n)*8 + (r-8)] = f2bf(acc);
        } else {
            vB[((size_t)b*64 + (r-16))*4096 + n] = f2bf(acc);
        }
    }
}

// Single-pass online-softmax MFMA flash, 4-way j-split across blockIdx.y.
// Per wave: 16 queries x 32 channels over 1024 j. Swapped-operand QK^T
// (S^T = K·Q, Q pre-scaled by log2e) so P is lane-local in PV B-frag layout.
// K-row permutation f0(m)=2m-(m&3): C/D reg r of tile t == B-frag elem 4t+r.
// Writes unnormalized acc + per-query (m, l) partials (log2 domain).
__global__ __launch_bounds__(256, 8) void flash_split_kernel(
    const unsigned short* __restrict__ qT, const unsigned short* __restrict__ kT,
    const unsigned short* __restrict__ vB,
    float* __restrict__ accO0, float* __restrict__ accP,
    float* __restrict__ mP, float* __restrict__ lP) {
    int b = blockIdx.z;
    int js = blockIdx.y;
    int tid = threadIdx.x;
    int w = tid >> 6, ln = tid & 63;
    int iw = w & 1, cw = w >> 1;
    int li = ln & 15, g = ln >> 4;
    int i0 = blockIdx.x * 32 + iw * 16;
    int c0 = cw * 32;

    const unsigned short* qTb = qT + (size_t)b * 4096 * 8;
    const unsigned short* kTb = kT + (size_t)b * 4096 * 8;
    const unsigned short* vBb = vB + (size_t)b * 64 * 4096;

    const short8v zf = {0,0,0,0,0,0,0,0};
    short8v qf = zf;
    if (g == 0) qf = *(const short8v*)(qTb + (size_t)(i0 + li) * 8);

    int jp = 2*li - (li & 3);    // f0(li)

    const unsigned short* vrow0 = vBb + (size_t)(c0 + li) * 4096 + 8*g;
    const unsigned short* vrow1 = vBb + (size_t)(c0 + 16 + li) * 4096 + 8*g;

    float m_run = -1e30f;
    float lsum = 0.f;
    float4v acc0 = {0.f,0.f,0.f,0.f}, acc1 = {0.f,0.f,0.f,0.f};

    int jbase = js * 1024;
    for (int j0 = jbase; j0 < jbase + 1024; j0 += 32) {
        short8v kf0 = zf, kf1 = zf;
        if (g == 0) {
            kf0 = *(const short8v*)(kTb + (size_t)(j0 + jp) * 8);
            kf1 = *(const short8v*)(kTb + (size_t)(j0 + jp + 4) * 8);
        }
        short8v vf0 = *(const short8v*)(vrow0 + j0);
        short8v vf1 = *(const short8v*)(vrow1 + j0);
        float4v s0 = {0.f,0.f,0.f,0.f}, s1 = {0.f,0.f,0.f,0.f};
        s0 = __builtin_amdgcn_mfma_f32_16x16x32_bf16(kf0, qf, s0, 0, 0, 0);
        s1 = __builtin_amdgcn_mfma_f32_16x16x32_bf16(kf1, qf, s1, 0, 0, 0);

        // per-query tile max (sync across the 4 g-groups of query li)
        float pm = fmaxf(fmaxf(fmaxf(s0[0], s0[1]), fmaxf(s0[2], s0[3])),
                         fmaxf(fmaxf(s1[0], s1[1]), fmaxf(s1[2], s1[3])));
        pm = fmaxf(pm, __shfl_xor(pm, 16));
        pm = fmaxf(pm, __shfl_xor(pm, 32));
        if (pm > m_run + DEFER_THR) {       // defer-max: rescale only on big growth
            float f = fexp2(m_run - pm);
            m_run = pm;
            lsum *= f;
            acc0[0] *= f; acc0[1] *= f; acc0[2] *= f; acc0[3] *= f;
            acc1[0] *= f; acc1[1] *= f; acc1[2] *= f; acc1[3] *= f;
        }

        float p0 = fexp2(s0[0] - m_run), p1 = fexp2(s0[1] - m_run);
        float p2 = fexp2(s0[2] - m_run), p3 = fexp2(s0[3] - m_run);
        float p4 = fexp2(s1[0] - m_run), p5 = fexp2(s1[1] - m_run);
        float p6 = fexp2(s1[2] - m_run), p7 = fexp2(s1[3] - m_run);
        lsum += ((p0 + p1) + (p2 + p3)) + ((p4 + p5) + (p6 + p7));
        uint4v pi;
        pi[0] = cvtpk_bf16(p0, p1);
        pi[1] = cvtpk_bf16(p2, p3);
        pi[2] = cvtpk_bf16(p4, p5);
        pi[3] = cvtpk_bf16(p6, p7);
        short8v pf = __builtin_bit_cast(short8v, pi);
        acc0 = __builtin_amdgcn_mfma_f32_16x16x32_bf16(vf0, pf, acc0, 0, 0, 0);
        acc1 = __builtin_amdgcn_mfma_f32_16x16x32_bf16(vf1, pf, acc1, 0, 0, 0);
    }
    lsum += __shfl_xor(lsum, 16);
    lsum += __shfl_xor(lsum, 32);

    float* accO = (js == 0) ? accO0 : (accP + (size_t)(js - 1) * 1048576);
    int i = i0 + li;
    #pragma unroll
    for (int r = 0; r < 4; ++r) {
        int c = c0 + 4*g + r;
        accO[((size_t)(b*64 + c)) * 4096 + i] = acc0[r];
        accO[((size_t)(b*64 + c + 16)) * 4096 + i] = acc1[r];
    }
    if (cw == 0 && g == 0) {
        mP[(size_t)(b*4 + js)*4096 + i] = m_run;
        lP[(size_t)(b*4 + js)*4096 + i] = lsum;
    }
}

// Combine the four j-splits (log-sum-exp merge), apply gamma/l and residual.
// In-place over acc0io (becomes hout).
__global__ void merge_kernel(float* __restrict__ acc0io, const float* __restrict__ accP,
                             const float* __restrict__ mP, const float* __restrict__ lP,
                             const float* __restrict__ hin,
                             const float* __restrict__ gammas, int a) {
    int idx = blockIdx.x * 256 + threadIdx.x;   // 1M
    int i = idx & 4095, b = idx >> 18;
    float m0 = mP[(size_t)(b*4 + 0)*4096 + i], m1 = mP[(size_t)(b*4 + 1)*4096 + i];
    float m2 = mP[(size_t)(b*4 + 2)*4096 + i], m3 = mP[(size_t)(b*4 + 3)*4096 + i];
    float l0 = lP[(size_t)(b*4 + 0)*4096 + i], l1 = lP[(size_t)(b*4 + 1)*4096 + i];
    float l2 = lP[(size_t)(b*4 + 2)*4096 + i], l3 = lP[(size_t)(b*4 + 3)*4096 + i];
    float M = fmaxf(fmaxf(m0, m1), fmaxf(m2, m3));
    float w0 = fexp2(m0 - M), w1 = fexp2(m1 - M);
    float w2 = fexp2(m2 - M), w3 = fexp2(m3 - M);
    float l = l0*w0 + l1*w1 + l2*w2 + l3*w3;
    float num = acc0io[idx]*w0 + accP[idx]*w1
              + accP[idx + 1048576]*w2 + accP[idx + 2097152]*w3;
    acc0io[idx] = num * (gammas[a] / l) + hin[idx];
}

__global__ void proj_kernel(const float* __restrict__ h, const float* __restrict__ ow,
                            const float* __restrict__ ob, float* __restrict__ out) {
    // 256 blocks: block = b*64 + chunk; 4 lanes per output
    int blk = blockIdx.x;
    int b = blk >> 6, ch = blk & 63;
    int tid = threadIdx.x;
    int hw = ch*64 + (tid & 63), cs = tid >> 6;
    float acc = 0.f;
    #pragma unroll 4
    for (int c = cs; c < 64; c += 4) acc += ow[c] * h[(size_t)(b*64 + c)*4096 + hw];
    __shared__ float red[4][64];
    red[cs][tid & 63] = acc;
    __syncthreads();
    if (tid < 64) {
        float s = red[0][tid] + red[1][tid] + red[2][tid] + red[3][tid] + ob[0];
        out[(size_t)b*4096 + ch*64 + tid] = s;
    }
}

extern "C" void kernel_launch(void* const* d_in, const int* in_sizes, int n_in,
                              void* d_out, int out_size, void* d_ws, size_t ws_size,
                              hipStream_t stream) {
    const float* x    = (const float*)d_in[0];
    const float* c1w  = (const float*)d_in[1];
    const float* bn1g = (const float*)d_in[2];
    const float* bn1b = (const float*)d_in[3];
    const float* c2w  = (const float*)d_in[4];
    const float* bn2g = (const float*)d_in[5];
    const float* bn2b = (const float*)d_in[6];
    const float* qw   = (const float*)d_in[7];
    const float* qbb  = (const float*)d_in[8];
    const float* kw   = (const float*)d_in[9];
    const float* kbb  = (const float*)d_in[10];
    const float* vw   = (const float*)d_in[11];
    const float* vbb  = (const float*)d_in[12];
    const float* gam  = (const float*)d_in[13];
    const float* ow   = (const float*)d_in[14];
    const float* ob   = (const float*)d_in[15];
    float* out = (float*)d_out;

    float* t1 = (float*)d_ws;                       // [4][64][4096] f32
    float* t2 = t1 + 1048576;                       // [4][64][4096] f32
    unsigned short* qT = (unsigned short*)(t2 + 1048576);  // [4][4096][8] bf16
    unsigned short* kT = qT + 131072;               // [4][4096][8] bf16
    unsigned short* vB = kT + 131072;               // [4][64][4096] bf16
    float* accP  = (float*)(vB + 1048576);          // 3 x [4][64][4096] f32 (split 1..3)
    float* mP    = accP + 3*1048576;                // [4][4][4096]
    float* lP    = mP + 65536;                      // [4][4][4096]
    float* stats = lP + 65536;                      // [128]
    float* ps    = stats + 128;                     // [512]

    conv1_kernel<<<4096, 256, 0, stream>>>(x, c1w, t1);
    stats_part_kernel<<<256, 256, 0, stream>>>(t1, ps);
    stats_final_kernel<<<1, 64, 0, stream>>>(ps, stats);
    bnrelu_kernel<<<4096, 256, 0, stream>>>(t1, stats, bn1g, bn1b);
    conv2_kernel<<<dim3(16,16,4), 256, 0, stream>>>(t1, c2w, t2);
    stats_part_kernel<<<256, 256, 0, stream>>>(t2, ps);
    stats_final_kernel<<<1, 64, 0, stream>>>(ps, stats);
    bnrelu_kernel<<<4096, 256, 0, stream>>>(t2, stats, bn2g, bn2b);

    float* cur = t2; float* oth = t1;
    for (int a = 0; a < 4; ++a) {
        qkv_kernel<<<dim3(64,4), 512, 0, stream>>>(cur, qw, qbb, kw, kbb, vw, vbb, a, qT, kT, vB);
        // split-0 partial goes into `oth`; merge finalizes in-place -> oth becomes hout
        flash_split_kernel<<<dim3(128,4,4), 256, 0, stream>>>(qT, kT, vB, oth, accP, mP, lP);
        merge_kernel<<<4096, 256, 0, stream>>>(oth, accP, mP, lP, cur, gam, a);
        float* tmp = cur; cur = oth; oth = tmp;
    }
    proj_kernel<<<256, 256, 0, stream>>>(cur, ow, ob, out);
}